// Round 2
// baseline (237.648 us; speedup 1.0000x reference)
//
#include <hip/hip_runtime.h>

// Problem constants
#define B_    16
#define N_    1024
#define DIN_  256
#define H_    4
#define F_    64
#define COUT_ 256
#define NEG_  0.2f

typedef __bf16 bf16x8 __attribute__((ext_vector_type(8)));
typedef float  f32x4  __attribute__((ext_vector_type(4)));
typedef unsigned short u16x8 __attribute__((ext_vector_type(8)));
typedef unsigned short u16x4 __attribute__((ext_vector_type(4)));

__device__ __forceinline__ unsigned short f2bf(float f) {
    unsigned u = __builtin_bit_cast(unsigned, f);
    u += 0x7fffu + ((u >> 16) & 1u);
    return (unsigned short)(u >> 16);
}

// ---------------------------------------------------------------------------
// Prep: blocks 0..255 transpose W -> Wt bf16 [H*F][DIN].
// Block 256: was/wad[h][d] = sum_f W[d,h,f] * a_{src,dst}[h,f]  (so that
// e_src[b,h,i] = x[b,i,:] . was[h,:] -- folds the logit projection into
// gat_h's K-loop and kills its shuffle-reduce epilogue).
// ---------------------------------------------------------------------------
__global__ __launch_bounds__(256) void prep_kernel(
    const float* __restrict__ W, const float* __restrict__ a_src,
    const float* __restrict__ a_dst, unsigned short* __restrict__ Wt,
    float* __restrict__ was, float* __restrict__ wad) {
    if (blockIdx.x < 256) {
        const int c = blockIdx.x, d = threadIdx.x;
        Wt[c * DIN_ + d] = f2bf(W[d * COUT_ + c]);
    } else {
        const int d = threadIdx.x;
        float s[H_] = {0.f, 0.f, 0.f, 0.f};
        float t[H_] = {0.f, 0.f, 0.f, 0.f};
#pragma unroll
        for (int h = 0; h < H_; h++) {
#pragma unroll
            for (int f = 0; f < F_; f += 4) {
                f32x4 wv = *(const f32x4*)(W + d * COUT_ + h * F_ + f);
                f32x4 av = *(const f32x4*)(a_src + h * F_ + f);
                f32x4 bv = *(const f32x4*)(a_dst + h * F_ + f);
                s[h] += wv[0]*av[0] + wv[1]*av[1] + wv[2]*av[2] + wv[3]*av[3];
                t[h] += wv[0]*bv[0] + wv[1]*bv[1] + wv[2]*bv[2] + wv[3]*bv[3];
            }
            was[h * DIN_ + d] = s[h];
            wad[h * DIN_ + d] = t[h];
        }
    }
}

// ---------------------------------------------------------------------------
// Kernel A: h = x @ W (bf16 MFMA), h_t stored [B][H][F][N]; e_src/e_dst
// computed in-loop as fp32 x . was/wad FMAs (head = wave).
// 16-row i-tile: grid = B*(N/16) = 1024 blocks = 4 blocks/CU at bounds(256,4).
// ---------------------------------------------------------------------------
__global__ __launch_bounds__(256, 4) void gat_h_kernel(
    const float* __restrict__ x, const unsigned short* __restrict__ Wt,
    const float* __restrict__ was, const float* __restrict__ wad,
    unsigned short* __restrict__ h_t, float* __restrict__ e_src,
    float* __restrict__ e_dst) {
    const int b   = blockIdx.x >> 6;
    const int it0 = (blockIdx.x & 63) * 16;
    const int w   = threadIdx.x >> 6;   // wave id == head
    const int ln  = threadIdx.x & 63;
    const int l15 = ln & 15;
    const int q   = ln >> 4;

    f32x4 acc[4];
#pragma unroll
    for (int ft = 0; ft < 4; ft++) acc[ft] = (f32x4)0.0f;
    float eps = 0.0f, epd = 0.0f;

    const float* xrow = x + (b * N_ + it0 + l15) * DIN_;

#pragma unroll 2
    for (int k0 = 0; k0 < DIN_; k0 += 32) {
        const int kb = k0 + q * 8;
        f32x4 xa = *(const f32x4*)(xrow + kb);
        f32x4 xb = *(const f32x4*)(xrow + kb + 4);
        f32x4 sa = *(const f32x4*)(was + w * DIN_ + kb);
        f32x4 sb = *(const f32x4*)(was + w * DIN_ + kb + 4);
        f32x4 da = *(const f32x4*)(wad + w * DIN_ + kb);
        f32x4 db = *(const f32x4*)(wad + w * DIN_ + kb + 4);
#pragma unroll
        for (int jj = 0; jj < 4; jj++) {
            eps += xa[jj] * sa[jj] + xb[jj] * sb[jj];
            epd += xa[jj] * da[jj] + xb[jj] * db[jj];
        }
        u16x8 u;
        u[0] = f2bf(xa[0]); u[1] = f2bf(xa[1]); u[2] = f2bf(xa[2]); u[3] = f2bf(xa[3]);
        u[4] = f2bf(xb[0]); u[5] = f2bf(xb[1]); u[6] = f2bf(xb[2]); u[7] = f2bf(xb[3]);
        bf16x8 af = __builtin_bit_cast(bf16x8, u);
#pragma unroll
        for (int ft = 0; ft < 4; ft++) {
            const int c = w * F_ + ft * 16 + l15;
            bf16x8 bf = *((const bf16x8*)(Wt + c * DIN_ + kb));
            acc[ft] = __builtin_amdgcn_mfma_f32_16x16x32_bf16(af, bf, acc[ft], 0, 0, 0);
        }
    }

    // Store h_t bf16: D row = q*4+r (local i), col = ft*16+l15 (f).
#pragma unroll
    for (int ft = 0; ft < 4; ft++) {
        u16x4 hb;
#pragma unroll
        for (int r = 0; r < 4; r++) hb[r] = f2bf(acc[ft][r]);
        const int f    = ft * 16 + l15;
        const int addr = ((b * H_ + w) * F_ + f) * N_ + it0 + q * 4;
        *((u16x4*)(h_t + addr)) = hb;
    }
    // e logits: reduce over q (k-subsets), row = it0 + l15.
    eps += __shfl_xor(eps, 16); eps += __shfl_xor(eps, 32);
    epd += __shfl_xor(epd, 16); epd += __shfl_xor(epd, 32);
    if (ln < 16) {
        e_src[(b * H_ + w) * N_ + it0 + ln] = eps;
        e_dst[(b * H_ + w) * N_ + it0 + ln] = epd;
    }
}

// ---------------------------------------------------------------------------
// Kernel C: fused mask/leaky/exp + (P @ h) MFMA + normalize + bias.
// 16-row i-tile, grid 1024, bounds(256,4); j-loop register double-buffered.
// ---------------------------------------------------------------------------
__global__ __launch_bounds__(256, 4) void gat_attn_kernel(
    const float* __restrict__ adj, const unsigned short* __restrict__ h_t,
    const float* __restrict__ e_src, const float* __restrict__ e_dst,
    const float* __restrict__ bias, float* __restrict__ out) {
    const int b   = blockIdx.x >> 6;
    const int it0 = (blockIdx.x & 63) * 16;
    const int w   = threadIdx.x >> 6;
    const int ln  = threadIdx.x & 63;
    const int l15 = ln & 15;
    const int q   = ln >> 4;

    const float edv = e_dst[(b * H_ + w) * N_ + it0 + l15];
    const float* es_base          = e_src + (b * H_ + w) * N_;
    const unsigned short* hb_base = h_t + ((b * H_ + w) * F_ + l15) * N_;
    const float* adj_row          = adj + (b * N_ + it0 + l15) * N_;

    f32x4 acc[4];
#pragma unroll
    for (int ft = 0; ft < 4; ft++) acc[ft] = (f32x4)0.0f;
    float rs = 0.0f;

    // Prime the register pipeline (j0 = 0).
    const int jb = q * 8;
    f32x4 c_e0 = *(const f32x4*)(es_base + jb);
    f32x4 c_e1 = *(const f32x4*)(es_base + jb + 4);
    f32x4 c_a0 = *(const f32x4*)(adj_row + jb);
    f32x4 c_a1 = *(const f32x4*)(adj_row + jb + 4);
    bf16x8 c_b[4];
#pragma unroll
    for (int ft = 0; ft < 4; ft++)
        c_b[ft] = *((const bf16x8*)(hb_base + ft * 16 * N_ + jb));

    for (int j0 = 0; j0 < N_; j0 += 32) {
        f32x4 n_e0, n_e1, n_a0, n_a1;
        bf16x8 n_b[4];
        const bool more = (j0 + 32) < N_;
        if (more) {  // uniform branch: issue next-iter loads before compute
            const int jn = j0 + 32 + jb;
            n_e0 = *(const f32x4*)(es_base + jn);
            n_e1 = *(const f32x4*)(es_base + jn + 4);
            n_a0 = *(const f32x4*)(adj_row + jn);
            n_a1 = *(const f32x4*)(adj_row + jn + 4);
#pragma unroll
            for (int ft = 0; ft < 4; ft++)
                n_b[ft] = *((const bf16x8*)(hb_base + ft * 16 * N_ + jn));
        }

        float es8[8] = {c_e0[0], c_e0[1], c_e0[2], c_e0[3], c_e1[0], c_e1[1], c_e1[2], c_e1[3]};
        float av8[8] = {c_a0[0], c_a0[1], c_a0[2], c_a0[3], c_a1[0], c_a1[1], c_a1[2], c_a1[3]};
        u16x8 u;
        float rloc = 0.0f;
#pragma unroll
        for (int jj = 0; jj < 8; jj++) {
            float t = edv + es8[jj];
            t = fmaxf(t, 0.0f) + NEG_ * fminf(t, 0.0f);   // leaky_relu
            float pe = __expf(t);
            float pv = (av8[jj] > 0.5f) ? pe : 0.0f;
            rloc += pv;
            __bf16 pb = (__bf16)pv;                        // HW cvt on gfx950
            u[jj] = __builtin_bit_cast(unsigned short, pb);
        }
        rs += rloc;
        bf16x8 afr = __builtin_bit_cast(bf16x8, u);
#pragma unroll
        for (int ft = 0; ft < 4; ft++)
            acc[ft] = __builtin_amdgcn_mfma_f32_16x16x32_bf16(afr, c_b[ft], acc[ft], 0, 0, 0);

        if (more) {
            c_e0 = n_e0; c_e1 = n_e1; c_a0 = n_a0; c_a1 = n_a1;
#pragma unroll
            for (int ft = 0; ft < 4; ft++) c_b[ft] = n_b[ft];
        }
    }

    // Full row sums: reduce over q; every lane gets sum for row it0+l15.
    rs += __shfl_xor(rs, 16);
    rs += __shfl_xor(rs, 32);
    // D rows are i = it0 + q*4 + r -> pull that row's sum from lane q*4+r.
    float rinv[4];
#pragma unroll
    for (int r = 0; r < 4; r++) rinv[r] = 1.0f / __shfl(rs, q * 4 + r);

    float bias_v[4];
#pragma unroll
    for (int ft = 0; ft < 4; ft++) bias_v[ft] = bias[w * F_ + ft * 16 + l15];

#pragma unroll
    for (int ft = 0; ft < 4; ft++)
#pragma unroll
        for (int r = 0; r < 4; r++) {
            const int i = it0 + q * 4 + r;
            const int c = w * F_ + ft * 16 + l15;
            out[(b * N_ + i) * COUT_ + c] = acc[ft][r] * rinv[r] + bias_v[ft];
        }
}

// ---------------------------------------------------------------------------
// Workspace layout (bytes):
//   [0, 128K)        Wt   bf16 [256][256]
//   [128K, +4K)      was  f32 [H][DIN]
//   [+4K, +4K)       wad  f32 [H][DIN]
//   [136K, +8M)      h_t  bf16 [B][H][F][N]
//   [+8M, +256K)     e_src f32 [B][H][N]
//   [+256K, +256K)   e_dst f32 [B][H][N]
// ---------------------------------------------------------------------------
extern "C" void kernel_launch(void* const* d_in, const int* in_sizes, int n_in,
                              void* d_out, int out_size, void* d_ws, size_t ws_size,
                              hipStream_t stream) {
    const float* x     = (const float*)d_in[0];
    const float* adj   = (const float*)d_in[1];
    const float* W     = (const float*)d_in[2];
    const float* a_src = (const float*)d_in[3];
    const float* a_dst = (const float*)d_in[4];
    const float* bias  = (const float*)d_in[5];
    float* out = (float*)d_out;

    char* ws = (char*)d_ws;
    unsigned short* Wt  = (unsigned short*)ws;
    float* was          = (float*)(ws + 131072);
    float* wad          = (float*)(ws + 131072 + 4096);
    unsigned short* h_t = (unsigned short*)(ws + 131072 + 8192);
    float* e_src        = (float*)(ws + 131072 + 8192 + 8388608);
    float* e_dst        = (float*)(ws + 131072 + 8192 + 8388608 + 262144);

    prep_kernel<<<257, 256, 0, stream>>>(W, a_src, a_dst, Wt, was, wad);
    gat_h_kernel<<<B_ * (N_ / 16), 256, 0, stream>>>(x, Wt, was, wad, h_t, e_src, e_dst);
    gat_attn_kernel<<<B_ * (N_ / 16), 256, 0, stream>>>(adj, h_t, e_src, e_dst, bias, out);
}